// Round 1
// baseline (303.761 us; speedup 1.0000x reference)
//
#include <hip/hip_runtime.h>
#include <hip/hip_bf16.h>
#include <math.h>

#define Mm 400
#define Cc 8
#define Ww 100
#define Dd 300
#define Hh 100
#define Rr 25
#define MC 3200   // M*C
#define LBP_ITERS 5

// ---------------------------------------------------------------------------
// Kernel 1: entity-context attention -> scores[m][c]
// One block per mention m, 128 threads.
// ---------------------------------------------------------------------------
__global__ __launch_bounds__(128) void k_entity_context(
    const float* __restrict__ ctxt_vec,   // [M][W][D]
    const float* __restrict__ cand_vec,   // [M][C][D]
    const float* __restrict__ A,          // [D]
    const float* __restrict__ B,          // [D]
    float* __restrict__ scores)           // [M*C]
{
  const int m = blockIdx.x;
  const int tid = threadIdx.x;
  __shared__ float Ae[Cc * Dd];     // A-scaled candidate vectors
  __shared__ float u_s[Ww];
  __shared__ float tmp_s[Ww];
  __shared__ float beta_s[Ww];
  __shared__ float cfB[Dd];
  __shared__ float red_s[2];

  const float* cev = cand_vec + (size_t)m * Cc * Dd;
  for (int idx = tid; idx < Cc * Dd; idx += 128)
    Ae[idx] = cev[idx] * A[idx % Dd];
  __syncthreads();

  // u[w] = max_c <A*e_c, ctxt_w>
  const float* cw = ctxt_vec + (size_t)m * Ww * Dd;
  if (tid < Ww) {
    float acc[Cc];
#pragma unroll
    for (int c = 0; c < Cc; ++c) acc[c] = 0.f;
    const float* row = cw + tid * Dd;
    for (int d = 0; d < Dd; ++d) {
      float x = row[d];
#pragma unroll
      for (int c = 0; c < Cc; ++c) acc[c] += Ae[c * Dd + d] * x;
    }
    float u = acc[0];
#pragma unroll
    for (int c = 1; c < Cc; ++c) u = fmaxf(u, acc[c]);
    u_s[tid] = u;
    tmp_s[tid] = u;
  }
  __syncthreads();

  // 25th largest (with multiplicity) via iterative max-removal, wave 0
  for (int r = 0; r < Rr; ++r) {
    if (tid < 64) {
      float v = -1e30f; int idx = 0;
      for (int j = tid; j < Ww; j += 64) {
        float t = tmp_s[j];
        if (t > v) { v = t; idx = j; }
      }
#pragma unroll
      for (int off = 32; off; off >>= 1) {
        float ov = __shfl_down(v, off);
        int   oi = __shfl_down(idx, off);
        if (ov > v) { v = ov; idx = oi; }
      }
      if (tid == 0) { tmp_s[idx] = -1e30f; if (r == Rr - 1) red_s[0] = v; }
    }
    __syncthreads();
  }
  float sketch = red_s[0];

  // Threshold(0,-50) then softmax over W
  if (tid < Ww) {
    float u = u_s[tid];
    tmp_s[tid] = (u > sketch) ? u : (sketch - 50.0f);
  }
  __syncthreads();
  if (tid < 64) {
    float mx = -1e30f;
    for (int j = tid; j < Ww; j += 64) mx = fmaxf(mx, tmp_s[j]);
#pragma unroll
    for (int off = 32; off; off >>= 1) mx = fmaxf(mx, __shfl_down(mx, off));
    if (tid == 0) red_s[0] = mx;
  }
  __syncthreads();
  float mx = red_s[0];
  if (tid < Ww) { float e = expf(tmp_s[tid] - mx); beta_s[tid] = e; tmp_s[tid] = e; }
  __syncthreads();
  if (tid < 64) {
    float s = 0.f;
    for (int j = tid; j < Ww; j += 64) s += tmp_s[j];
#pragma unroll
    for (int off = 32; off; off >>= 1) s += __shfl_down(s, off);
    if (tid == 0) red_s[1] = s;
  }
  __syncthreads();
  float inv = 1.0f / red_s[1];

  // ctxt_full * B
  for (int d = tid; d < Dd; d += 128) {
    float cf = 0.f;
    for (int w = 0; w < Ww; ++w) cf += beta_s[w] * cw[w * Dd + d];
    cfB[d] = cf * inv * B[d];
  }
  __syncthreads();

  // scores[m][c] = <e_c, cfB>
  int c = tid >> 4, lane = tid & 15;
  float p = 0.f;
  for (int d = lane; d < Dd; d += 16) p += cev[c * Dd + d] * cfB[d];
#pragma unroll
  for (int off = 8; off; off >>= 1) p += __shfl_down(p, off, 16);
  if (lane == 0) scores[m * Cc + c] = p;
}

// ---------------------------------------------------------------------------
// Kernel 2: P = (X ⊙ Cl) @ X^T   [3200 x 3200], K=300, fp32 vector FMA
// 64x64 tile per block, 256 threads, 4x4 per thread.
// ---------------------------------------------------------------------------
__global__ __launch_bounds__(256) void k_pairwise(
    const float* __restrict__ X,   // [MC][D]
    const float* __restrict__ Cl,  // [D]
    float* __restrict__ P)         // [MC][MC]
{
  __shared__ __align__(16) float As[16][64];
  __shared__ __align__(16) float Bs[16][64];
  const int bj = blockIdx.x, bi = blockIdx.y;
  const int tid = threadIdx.x;
  const int tx = tid & 15, ty = tid >> 4;
  const int row0 = bi * 64, col0 = bj * 64;
  float acc[4][4] = {};

  for (int k0 = 0; k0 < Dd; k0 += 16) {
#pragma unroll
    for (int l = 0; l < 4; ++l) {
      int idx = tid + l * 256;
      int r = idx >> 4, c = idx & 15;
      int gk = k0 + c;
      float va = 0.f, vb = 0.f;
      if (gk < Dd) {
        va = X[(size_t)(row0 + r) * Dd + gk] * Cl[gk];
        vb = X[(size_t)(col0 + r) * Dd + gk];
      }
      As[c][r] = va;
      Bs[c][r] = vb;
    }
    __syncthreads();
#pragma unroll
    for (int k = 0; k < 16; ++k) {
      float4 a4 = *reinterpret_cast<const float4*>(&As[k][ty * 4]);
      float4 b4 = *reinterpret_cast<const float4*>(&Bs[k][tx * 4]);
      float a[4] = {a4.x, a4.y, a4.z, a4.w};
      float b[4] = {b4.x, b4.y, b4.z, b4.w};
#pragma unroll
      for (int i = 0; i < 4; ++i)
#pragma unroll
        for (int j = 0; j < 4; ++j) acc[i][j] += a[i] * b[j];
    }
    __syncthreads();
  }
#pragma unroll
  for (int i = 0; i < 4; ++i) {
    float4 v = make_float4(acc[i][0], acc[i][1], acc[i][2], acc[i][3]);
    *reinterpret_cast<float4*>(&P[(size_t)(row0 + ty * 4 + i) * MC + col0 + tx * 4]) = v;
  }
}

// ---------------------------------------------------------------------------
// LBP: col[j] = scores[j] + sum_a msg[j][a]    (j = m*C+c)
// one wave per j
// ---------------------------------------------------------------------------
__global__ __launch_bounds__(256) void k_col(
    const float* __restrict__ msg,    // [MC][M]
    const float* __restrict__ scores, // [MC]
    float* __restrict__ col)          // [MC]
{
  int j = blockIdx.x * 4 + (threadIdx.x >> 6);
  int lane = threadIdx.x & 63;
  const float* row = msg + (size_t)j * Mm;
  float s = 0.f;
  for (int a = lane; a < Mm; a += 64) s += row[a];
#pragma unroll
  for (int off = 32; off; off >>= 1) s += __shfl_down(s, off);
  if (lane == 0) col[j] = scores[j] + s;
}

// ---------------------------------------------------------------------------
// LBP step: for each (a,b,m):
//   t = max_c (P[a*8+b][m*8+c] + col[m*8+c])
//   sel = log_softmax_b(t);  sel[a,b,a] = 0
//   msg = log(0.5*exp(sel) + 0.5*exp(msg_old))
// one block per a, 256 threads over m
// ---------------------------------------------------------------------------
__global__ __launch_bounds__(256) void k_lbp(
    const float* __restrict__ P,
    const float* __restrict__ col,
    float* __restrict__ msg)
{
  const int aa = blockIdx.x;
  __shared__ __align__(16) float col_s[MC];
  for (int i = threadIdx.x; i < MC; i += 256) col_s[i] = col[i];
  __syncthreads();

  for (int m = threadIdx.x; m < Mm; m += 256) {
    const float4 c0 = *reinterpret_cast<const float4*>(&col_s[m * 8]);
    const float4 c1 = *reinterpret_cast<const float4*>(&col_s[m * 8 + 4]);
    float t[Cc];
#pragma unroll
    for (int b = 0; b < Cc; ++b) {
      const float* prow = P + (size_t)(aa * 8 + b) * MC + m * 8;
      float4 p0 = *reinterpret_cast<const float4*>(prow);
      float4 p1 = *reinterpret_cast<const float4*>(prow + 4);
      float tb = fmaxf(fmaxf(p0.x + c0.x, p0.y + c0.y), fmaxf(p0.z + c0.z, p0.w + c0.w));
      tb = fmaxf(tb, fmaxf(fmaxf(p1.x + c1.x, p1.y + c1.y), fmaxf(p1.z + c1.z, p1.w + c1.w)));
      t[b] = tb;
    }
    float mxt = t[0];
#pragma unroll
    for (int b = 1; b < Cc; ++b) mxt = fmaxf(mxt, t[b]);
    float se = 0.f;
#pragma unroll
    for (int b = 0; b < Cc; ++b) se += expf(t[b] - mxt);
    float lse = mxt + logf(se);
    bool self = (m == aa);
#pragma unroll
    for (int b = 0; b < Cc; ++b) {
      float sel = self ? 0.f : (t[b] - lse);
      size_t mi = (size_t)(aa * 8 + b) * Mm + m;
      float old = msg[mi];
      msg[mi] = logf(0.5f * expf(sel) + 0.5f * expf(old));
    }
  }
}

// ---------------------------------------------------------------------------
// Final: gm = msg.sum(axis=2); fgs = log_softmax(scores+gm, axis=C); MLP
// one block (one wave) per mention
// ---------------------------------------------------------------------------
__global__ __launch_bounds__(64) void k_final(
    const float* __restrict__ msg,     // [MC][M]
    const float* __restrict__ scores,  // [MC]
    const float* __restrict__ pem,     // [MC]
    const float* __restrict__ W1,      // [H][2]
    const float* __restrict__ b1,      // [H]
    const float* __restrict__ W2,      // [H]
    const float* __restrict__ b2,      // [1]
    float* __restrict__ out)           // [MC]
{
  const int m = blockIdx.x;
  const int lane = threadIdx.x;
  __shared__ float f_s[Cc];

  for (int c = 0; c < Cc; ++c) {
    const float* row = msg + (size_t)(m * Cc + c) * Mm;
    float s = 0.f;
    for (int a = lane; a < Mm; a += 64) s += row[a];
#pragma unroll
    for (int off = 32; off; off >>= 1) s += __shfl_down(s, off);
    if (lane == 0) f_s[c] = scores[m * Cc + c] + s;
  }
  __syncthreads();

  if (lane < Cc) {
    float f = f_s[lane];
    float mx = f;
#pragma unroll
    for (int off = 4; off; off >>= 1) mx = fmaxf(mx, __shfl_xor(mx, off, 8));
    float se = expf(f - mx);
#pragma unroll
    for (int off = 4; off; off >>= 1) se += __shfl_xor(se, off, 8);
    float fgs = f - mx - logf(se);
    float pm = pem[m * Cc + lane];
    float acc = b2[0];
    for (int h = 0; h < Hh; ++h) {
      float z = fgs * W1[2 * h] + pm * W1[2 * h + 1] + b1[h];
      acc += W2[h] * fmaxf(z, 0.f);
    }
    out[m * Cc + lane] = acc;
  }
}

// ---------------------------------------------------------------------------
extern "C" void kernel_launch(void* const* d_in, const int* in_sizes, int n_in,
                              void* d_out, int out_size, void* d_ws, size_t ws_size,
                              hipStream_t stream) {
  const float* ctxt_vec = (const float*)d_in[1];   // [M][W][D]
  const float* cand_vec = (const float*)d_in[3];   // [M][C][D]
  const float* pem      = (const float*)d_in[4];   // [M][C]
  const float* A        = (const float*)d_in[5];
  const float* B        = (const float*)d_in[6];
  const float* Cl       = (const float*)d_in[7];
  const float* W1       = (const float*)d_in[8];
  const float* b1       = (const float*)d_in[9];
  const float* W2       = (const float*)d_in[10];
  const float* b2       = (const float*)d_in[11];
  float* out = (float*)d_out;

  char* ws = (char*)d_ws;
  float* P      = (float*)(ws);                              // 3200*3200*4 = 40,960,000 B
  float* msg    = (float*)(ws + 40960000);                   // 3200*400*4  =  5,120,000 B
  float* col    = (float*)(ws + 40960000 + 5120000);         // 3200*4
  float* scores = col + MC;                                  // 3200*4

  hipMemsetAsync(msg, 0, (size_t)MC * Mm * sizeof(float), stream);

  k_entity_context<<<Mm, 128, 0, stream>>>(ctxt_vec, cand_vec, A, B, scores);

  dim3 g(MC / 64, MC / 64);
  k_pairwise<<<g, 256, 0, stream>>>(cand_vec, Cl, P);

  for (int it = 0; it < LBP_ITERS; ++it) {
    k_col<<<MC / 4, 256, 0, stream>>>(msg, scores, col);
    k_lbp<<<Mm, 256, 0, stream>>>(P, col, msg);
  }

  k_final<<<Mm, 64, 0, stream>>>(msg, scores, pem, W1, b1, W2, b2, out);
}

// Round 2
// 172.674 us; speedup vs baseline: 1.7592x; 1.7592x over previous
//
#include <hip/hip_runtime.h>
#include <hip/hip_bf16.h>
#include <math.h>

#define Mm 400
#define Cc 8
#define Ww 100
#define Dd 300
#define Hh 100
#define Rr 25
#define MC 3200   // M*C
#define KP 320    // K padded to multiple of 32
#define LBP_ITERS 5

typedef __bf16 bf16x8 __attribute__((ext_vector_type(8)));
typedef float f32x4 __attribute__((ext_vector_type(4)));

__device__ __forceinline__ void gload16(const void* g, void* l) {
  __builtin_amdgcn_global_load_lds(
      (const __attribute__((address_space(1))) void*)g,
      (__attribute__((address_space(3))) void*)l, 16, 0, 0);
}

// ---------------------------------------------------------------------------
// Kernel 1: entity-context attention -> scores[m][c]; also seeds col0 = scores
// One block per mention m, 128 threads.
// ---------------------------------------------------------------------------
__global__ __launch_bounds__(128) void k_entity_context(
    const float* __restrict__ ctxt_vec,   // [M][W][D]
    const float* __restrict__ cand_vec,   // [M][C][D]
    const float* __restrict__ A,          // [D]
    const float* __restrict__ B,          // [D]
    float* __restrict__ scores,           // [M*C]
    float* __restrict__ col0)             // [M*C]
{
  const int m = blockIdx.x;
  const int tid = threadIdx.x;
  __shared__ float Ae[Cc * Dd];
  __shared__ float u_s[Ww];
  __shared__ float tmp_s[Ww];
  __shared__ float beta_s[Ww];
  __shared__ float cfB[Dd];
  __shared__ float red_s[2];

  const float* cev = cand_vec + (size_t)m * Cc * Dd;
  for (int idx = tid; idx < Cc * Dd; idx += 128)
    Ae[idx] = cev[idx] * A[idx % Dd];
  __syncthreads();

  const float* cw = ctxt_vec + (size_t)m * Ww * Dd;
  if (tid < Ww) {
    float acc[Cc];
#pragma unroll
    for (int c = 0; c < Cc; ++c) acc[c] = 0.f;
    const float* row = cw + tid * Dd;
    for (int d = 0; d < Dd; ++d) {
      float x = row[d];
#pragma unroll
      for (int c = 0; c < Cc; ++c) acc[c] += Ae[c * Dd + d] * x;
    }
    float u = acc[0];
#pragma unroll
    for (int c = 1; c < Cc; ++c) u = fmaxf(u, acc[c]);
    u_s[tid] = u;
    tmp_s[tid] = u;
  }
  __syncthreads();

  // 25th largest (with multiplicity) via iterative max-removal
  for (int r = 0; r < Rr; ++r) {
    if (tid < 64) {
      float v = -1e30f; int idx = 0;
      for (int j = tid; j < Ww; j += 64) {
        float t = tmp_s[j];
        if (t > v) { v = t; idx = j; }
      }
#pragma unroll
      for (int off = 32; off; off >>= 1) {
        float ov = __shfl_down(v, off);
        int   oi = __shfl_down(idx, off);
        if (ov > v) { v = ov; idx = oi; }
      }
      if (tid == 0) { tmp_s[idx] = -1e30f; if (r == Rr - 1) red_s[0] = v; }
    }
    __syncthreads();
  }
  float sketch = red_s[0];

  if (tid < Ww) {
    float u = u_s[tid];
    tmp_s[tid] = (u > sketch) ? u : (sketch - 50.0f);
  }
  __syncthreads();
  if (tid < 64) {
    float mx = -1e30f;
    for (int j = tid; j < Ww; j += 64) mx = fmaxf(mx, tmp_s[j]);
#pragma unroll
    for (int off = 32; off; off >>= 1) mx = fmaxf(mx, __shfl_down(mx, off));
    if (tid == 0) red_s[0] = mx;
  }
  __syncthreads();
  float mx = red_s[0];
  if (tid < Ww) { float e = expf(tmp_s[tid] - mx); beta_s[tid] = e; tmp_s[tid] = e; }
  __syncthreads();
  if (tid < 64) {
    float s = 0.f;
    for (int j = tid; j < Ww; j += 64) s += tmp_s[j];
#pragma unroll
    for (int off = 32; off; off >>= 1) s += __shfl_down(s, off);
    if (tid == 0) red_s[1] = s;
  }
  __syncthreads();
  float inv = 1.0f / red_s[1];

  for (int d = tid; d < Dd; d += 128) {
    float cf = 0.f;
    for (int w = 0; w < Ww; ++w) cf += beta_s[w] * cw[w * Dd + d];
    cfB[d] = cf * inv * B[d];
  }
  __syncthreads();

  int c = tid >> 4, lane = tid & 15;
  float p = 0.f;
  for (int d = lane; d < Dd; d += 16) p += cev[c * Dd + d] * cfB[d];
#pragma unroll
  for (int off = 8; off; off >>= 1) p += __shfl_down(p, off, 16);
  if (lane == 0) { scores[m * Cc + c] = p; col0[m * Cc + c] = p; }
}

// ---------------------------------------------------------------------------
// bf16 conversion: Ah = bf16(X*Cl), Bh = bf16(X), K padded 300->320 w/ zeros
// ---------------------------------------------------------------------------
__global__ __launch_bounds__(256) void k_convert(
    const float* __restrict__ X,   // [MC][D]
    const float* __restrict__ Cl,  // [D]
    __bf16* __restrict__ Ah,       // [MC][KP]
    __bf16* __restrict__ Bh)       // [MC][KP]
{
  int idx = blockIdx.x * 256 + threadIdx.x;
  if (idx >= MC * KP) return;
  int j = idx / KP, k = idx - j * KP;
  float x = 0.f, cl = 0.f;
  if (k < Dd) { x = X[(size_t)j * Dd + k]; cl = Cl[k]; }
  Bh[idx] = (__bf16)x;
  Ah[idx] = (__bf16)(x * cl);
}

// ---------------------------------------------------------------------------
// Kernel 2: P = Ah @ Bh^T  [3200 x 3200], K=320, bf16 MFMA, fp32 accum
// 128x128 tile, 4 waves (2x2), each wave 64x64 via 4x4 16x16x32 fragments.
// ---------------------------------------------------------------------------
__global__ __launch_bounds__(256) void k_pairwise_mfma(
    const __bf16* __restrict__ Ah,  // [MC][KP]
    const __bf16* __restrict__ Bh,  // [MC][KP]
    float* __restrict__ P)          // [MC][MC]
{
  __shared__ __align__(16) __bf16 As[128 * 32];  // 8 KB
  __shared__ __align__(16) __bf16 Bs[128 * 32];  // 8 KB
  const int tid = threadIdx.x;
  const int wave = tid >> 6, lane = tid & 63;
  const int wr = wave >> 1, wc = wave & 1;      // 2x2 wave grid
  const int row0 = blockIdx.y * 128, col0 = blockIdx.x * 128;

  f32x4 acc[4][4] = {};
  const int fr = lane & 15, fq = lane >> 4;
  const int koff = fq * 8;

  for (int kt = 0; kt < KP / 32; ++kt) {
    const int k0 = kt * 32;
    // stage A and B tiles: 8 KB each = 512 x 16B chunks, 2 per thread each
#pragma unroll
    for (int i = 0; i < 2; ++i) {
      int e = i * 256 + tid;
      int r = e >> 2;
      int kc = (e & 3) << 3;
      gload16(Ah + (size_t)(row0 + r) * KP + k0 + kc, (char*)As + e * 16);
      gload16(Bh + (size_t)(col0 + r) * KP + k0 + kc, (char*)Bs + e * 16);
    }
    __syncthreads();

    bf16x8 af[4], bfr[4];
#pragma unroll
    for (int mi = 0; mi < 4; ++mi)
      af[mi] = *(const bf16x8*)&As[(wr * 64 + mi * 16 + fr) * 32 + koff];
#pragma unroll
    for (int ni = 0; ni < 4; ++ni)
      bfr[ni] = *(const bf16x8*)&Bs[(wc * 64 + ni * 16 + fr) * 32 + koff];
#pragma unroll
    for (int mi = 0; mi < 4; ++mi)
#pragma unroll
      for (int ni = 0; ni < 4; ++ni)
        acc[mi][ni] = __builtin_amdgcn_mfma_f32_16x16x32_bf16(
            af[mi], bfr[ni], acc[mi][ni], 0, 0, 0);
    __syncthreads();
  }

  // epilogue: C/D layout col=lane&15, row=(lane>>4)*4+reg
#pragma unroll
  for (int mi = 0; mi < 4; ++mi)
#pragma unroll
    for (int ni = 0; ni < 4; ++ni) {
      size_t base = (size_t)(row0 + wr * 64 + mi * 16 + fq * 4) * MC +
                    col0 + wc * 64 + ni * 16 + fr;
#pragma unroll
      for (int r = 0; r < 4; ++r)
        P[base + (size_t)r * MC] = acc[mi][ni][r];
    }
}

// ---------------------------------------------------------------------------
// LBP step (fused col production):
//   t[b] = max_c (P[aa*8+b][m*8+c] + colIn[m*8+c])
//   sel = log_softmax_b(t); sel[.,.,aa] = 0
//   msg = log(0.5*exp(sel) + 0.5*exp(msg_old))
//   colOut[aa*8+b] = scores[aa*8+b] + sum_m msg_new
// ---------------------------------------------------------------------------
__global__ __launch_bounds__(256) void k_lbp(
    const float* __restrict__ P,
    const float* __restrict__ colIn,
    const float* __restrict__ scores,
    float* __restrict__ msg,
    float* __restrict__ colOut)
{
  const int aa = blockIdx.x;
  __shared__ __align__(16) float col_s[MC];
  __shared__ float red_s[4][Cc];
  for (int i = threadIdx.x; i < MC; i += 256) col_s[i] = colIn[i];
  __syncthreads();

  float psum[Cc];
#pragma unroll
  for (int b = 0; b < Cc; ++b) psum[b] = 0.f;

  for (int m = threadIdx.x; m < Mm; m += 256) {
    const float4 c0 = *reinterpret_cast<const float4*>(&col_s[m * 8]);
    const float4 c1 = *reinterpret_cast<const float4*>(&col_s[m * 8 + 4]);
    float t[Cc];
#pragma unroll
    for (int b = 0; b < Cc; ++b) {
      const float* prow = P + (size_t)(aa * 8 + b) * MC + m * 8;
      float4 p0 = *reinterpret_cast<const float4*>(prow);
      float4 p1 = *reinterpret_cast<const float4*>(prow + 4);
      float tb = fmaxf(fmaxf(p0.x + c0.x, p0.y + c0.y), fmaxf(p0.z + c0.z, p0.w + c0.w));
      t[b] = fmaxf(tb, fmaxf(fmaxf(p1.x + c1.x, p1.y + c1.y), fmaxf(p1.z + c1.z, p1.w + c1.w)));
    }
    float mxt = t[0];
#pragma unroll
    for (int b = 1; b < Cc; ++b) mxt = fmaxf(mxt, t[b]);
    float se = 0.f;
#pragma unroll
    for (int b = 0; b < Cc; ++b) se += expf(t[b] - mxt);
    float lse = mxt + logf(se);
    bool self = (m == aa);
#pragma unroll
    for (int b = 0; b < Cc; ++b) {
      float sel = self ? 0.f : (t[b] - lse);
      size_t mi = (size_t)(aa * 8 + b) * Mm + m;
      float old = msg[mi];
      float nv = logf(0.5f * expf(sel) + 0.5f * expf(old));
      msg[mi] = nv;
      psum[b] += nv;
    }
  }

  const int wave = threadIdx.x >> 6, lane = threadIdx.x & 63;
#pragma unroll
  for (int b = 0; b < Cc; ++b)
#pragma unroll
    for (int off = 32; off; off >>= 1) psum[b] += __shfl_down(psum[b], off);
  if (lane == 0)
#pragma unroll
    for (int b = 0; b < Cc; ++b) red_s[wave][b] = psum[b];
  __syncthreads();
  if (threadIdx.x < Cc) {
    int b = threadIdx.x;
    float s = red_s[0][b] + red_s[1][b] + red_s[2][b] + red_s[3][b];
    colOut[aa * Cc + b] = scores[aa * Cc + b] + s;
  }
}

// ---------------------------------------------------------------------------
// Final: fgs = log_softmax(colF, axis=C); tiny MLP. One thread per mention.
// ---------------------------------------------------------------------------
__global__ __launch_bounds__(64) void k_final2(
    const float* __restrict__ colF,    // [MC] = scores + global_message
    const float* __restrict__ pem,     // [MC]
    const float* __restrict__ W1,      // [H][2]
    const float* __restrict__ b1,      // [H]
    const float* __restrict__ W2,      // [H]
    const float* __restrict__ b2,      // [1]
    float* __restrict__ out)           // [MC]
{
  int m = blockIdx.x * 64 + threadIdx.x;
  if (m >= Mm) return;
  float f[Cc], pm[Cc];
#pragma unroll
  for (int c = 0; c < Cc; ++c) {
    f[c] = colF[m * Cc + c];
    pm[c] = pem[m * Cc + c];
  }
  float mx = f[0];
#pragma unroll
  for (int c = 1; c < Cc; ++c) mx = fmaxf(mx, f[c]);
  float se = 0.f;
#pragma unroll
  for (int c = 0; c < Cc; ++c) se += expf(f[c] - mx);
  float lse = mx + logf(se);
  float fgs[Cc], accv[Cc];
  float bb2 = b2[0];
#pragma unroll
  for (int c = 0; c < Cc; ++c) { fgs[c] = f[c] - lse; accv[c] = bb2; }
  for (int h = 0; h < Hh; ++h) {
    float w0 = W1[2 * h], w1 = W1[2 * h + 1], bb = b1[h], w2 = W2[h];
#pragma unroll
    for (int c = 0; c < Cc; ++c)
      accv[c] += w2 * fmaxf(fgs[c] * w0 + pm[c] * w1 + bb, 0.f);
  }
#pragma unroll
  for (int c = 0; c < Cc; ++c) out[m * Cc + c] = accv[c];
}

// ---------------------------------------------------------------------------
extern "C" void kernel_launch(void* const* d_in, const int* in_sizes, int n_in,
                              void* d_out, int out_size, void* d_ws, size_t ws_size,
                              hipStream_t stream) {
  const float* ctxt_vec = (const float*)d_in[1];   // [M][W][D]
  const float* cand_vec = (const float*)d_in[3];   // [M][C][D]
  const float* pem      = (const float*)d_in[4];   // [M][C]
  const float* A        = (const float*)d_in[5];
  const float* B        = (const float*)d_in[6];
  const float* Cl       = (const float*)d_in[7];
  const float* W1       = (const float*)d_in[8];
  const float* b1       = (const float*)d_in[9];
  const float* W2       = (const float*)d_in[10];
  const float* b2       = (const float*)d_in[11];
  float* out = (float*)d_out;

  char* ws = (char*)d_ws;
  float*  P      = (float*)(ws);                          // 40,960,000 B
  float*  msg    = (float*)(ws + 40960000);               //  5,120,000 B
  // Ah/Bh alias the msg region: only live until the GEMM completes; the
  // msg memset is stream-ordered after the GEMM.
  __bf16* Ah     = (__bf16*)(ws + 40960000);              //  2,048,000 B
  __bf16* Bh     = (__bf16*)(ws + 40960000 + 2048000);    //  2,048,000 B
  float*  scores = (float*)(ws + 46080000);               //     12,800 B
  float*  col0   = scores + MC;
  float*  col1   = col0 + MC;

  k_convert<<<(MC * KP + 255) / 256, 256, 0, stream>>>(cand_vec, Cl, Ah, Bh);
  k_entity_context<<<Mm, 128, 0, stream>>>(ctxt_vec, cand_vec, A, B, scores, col0);

  dim3 g(MC / 128, MC / 128);
  k_pairwise_mfma<<<g, 256, 0, stream>>>(Ah, Bh, P);

  hipMemsetAsync(msg, 0, (size_t)MC * Mm * sizeof(float), stream);  // after GEMM (alias!)

  float* cIn = col0; float* cOut = col1;
  for (int it = 0; it < LBP_ITERS; ++it) {
    k_lbp<<<Mm, 256, 0, stream>>>(P, cIn, scores, msg, cOut);
    float* t = cIn; cIn = cOut; cOut = t;
  }
  // after 5 iters, cIn points at the final col (= scores + global_message)
  k_final2<<<(Mm + 63) / 64, 64, 0, stream>>>(cIn, pem, W1, b1, W2, b2, out);
}

// Round 3
// 158.088 us; speedup vs baseline: 1.9215x; 1.0923x over previous
//
#include <hip/hip_runtime.h>
#include <hip/hip_bf16.h>
#include <math.h>

#define Mm 400
#define Cc 8
#define Ww 100
#define Dd 300
#define Hh 100
#define Rr 25
#define MC 3200   // M*C
#define KP 320    // K padded to multiple of 32
#define LBP_ITERS 5
#define WCHUNK 50 // w-rows staged in LDS per chunk

typedef __bf16 bf16x8 __attribute__((ext_vector_type(8)));
typedef float f32x4 __attribute__((ext_vector_type(4)));

__device__ __forceinline__ void gload16(const void* g, void* l) {
  __builtin_amdgcn_global_load_lds(
      (const __attribute__((address_space(1))) void*)g,
      (__attribute__((address_space(3))) void*)l, 16, 0, 0);
}

// ---------------------------------------------------------------------------
// Kernel 1: entity-context attention -> scores[m][c]; also seeds col0 = scores
// One block per mention m, 256 threads, LDS-staged ctxt rows.
// ---------------------------------------------------------------------------
__global__ __launch_bounds__(256) void k_entity_context(
    const float* __restrict__ ctxt_vec,   // [M][W][D]
    const float* __restrict__ cand_vec,   // [M][C][D]
    const float* __restrict__ A,          // [D]
    const float* __restrict__ B,          // [D]
    float* __restrict__ scores,           // [M*C]
    float* __restrict__ col0)             // [M*C]
{
  const int m = blockIdx.x;
  const int tid = threadIdx.x;
  __shared__ __align__(16) float cws[WCHUNK * Dd];   // 60 KB
  __shared__ __align__(16) float Ae[Cc * Dd];        // 9.6 KB
  __shared__ float u_s[Ww];
  __shared__ float tmp_s[Ww];
  __shared__ float beta_s[Ww];
  __shared__ float cfB[Dd];
  __shared__ float red_s[2];

  const float* cev = cand_vec + (size_t)m * Cc * Dd;
  for (int idx = tid; idx < Cc * Dd; idx += 256)
    Ae[idx] = cev[idx] * A[idx % Dd];

  const float* cw = ctxt_vec + (size_t)m * Ww * Dd;
  const int cg = tid & 3;          // c-pair index: c0=2cg, c1=2cg+1
  const int wl = tid >> 2;         // local w within chunk (0..63)

  // ---- u-phase: 2 chunks of 50 w-rows staged via global_load_lds ----
  for (int ch = 0; ch < Ww / WCHUNK; ++ch) {
    const int w0 = ch * WCHUNK;
    __syncthreads();  // cws free (prev chunk consumed), Ae ready after ch0
    // stage 50*300 floats = 3750 x 16B, contiguous
    for (int e = tid; e < WCHUNK * Dd / 4; e += 256)
      gload16(cw + (size_t)w0 * Dd + e * 4, (char*)cws + e * 16);
    __syncthreads();

    if (wl < WCHUNK) {
      const float* r = &cws[wl * Dd];
      const float* a0 = &Ae[(2 * cg) * Dd];
      const float* a1 = &Ae[(2 * cg + 1) * Dd];
      f32x4 s0 = {0.f, 0.f, 0.f, 0.f}, s1 = {0.f, 0.f, 0.f, 0.f};
      for (int d4 = 0; d4 < Dd / 4; ++d4) {
        f32x4 x = *(const f32x4*)&r[d4 * 4];
        f32x4 e0 = *(const f32x4*)&a0[d4 * 4];
        f32x4 e1 = *(const f32x4*)&a1[d4 * 4];
        s0 += x * e0;
        s1 += x * e1;
      }
      float d0 = s0[0] + s0[1] + s0[2] + s0[3];
      float d1 = s1[0] + s1[1] + s1[2] + s1[3];
      float v = fmaxf(d0, d1);
      v = fmaxf(v, __shfl_xor(v, 1, 4));
      v = fmaxf(v, __shfl_xor(v, 2, 4));
      if (cg == 0) { u_s[w0 + wl] = v; tmp_s[w0 + wl] = v; }
    }
  }
  __syncthreads();

  // ---- 25th largest (with multiplicity) via iterative max-removal ----
  for (int r = 0; r < Rr; ++r) {
    if (tid < 64) {
      float v = -1e30f; int idx = 0;
      for (int j = tid; j < Ww; j += 64) {
        float t = tmp_s[j];
        if (t > v) { v = t; idx = j; }
      }
#pragma unroll
      for (int off = 32; off; off >>= 1) {
        float ov = __shfl_down(v, off);
        int   oi = __shfl_down(idx, off);
        if (ov > v) { v = ov; idx = oi; }
      }
      if (tid == 0) { tmp_s[idx] = -1e30f; if (r == Rr - 1) red_s[0] = v; }
    }
    __syncthreads();
  }
  float sketch = red_s[0];

  if (tid < Ww) {
    float u = u_s[tid];
    tmp_s[tid] = (u > sketch) ? u : (sketch - 50.0f);
  }
  __syncthreads();
  if (tid < 64) {
    float mx = -1e30f;
    for (int j = tid; j < Ww; j += 64) mx = fmaxf(mx, tmp_s[j]);
#pragma unroll
    for (int off = 32; off; off >>= 1) mx = fmaxf(mx, __shfl_down(mx, off));
    if (tid == 0) red_s[0] = mx;
  }
  __syncthreads();
  float mx = red_s[0];
  if (tid < Ww) { float e = expf(tmp_s[tid] - mx); beta_s[tid] = e; tmp_s[tid] = e; }
  __syncthreads();
  if (tid < 64) {
    float s = 0.f;
    for (int j = tid; j < Ww; j += 64) s += tmp_s[j];
#pragma unroll
    for (int off = 32; off; off >>= 1) s += __shfl_down(s, off);
    if (tid == 0) red_s[1] = s;
  }
  __syncthreads();
  float inv = 1.0f / red_s[1];

  // ---- ctxt_full * B: thread = float2 column, coalesced L2 re-read ----
  if (tid < Dd / 2) {
    float2 cf = make_float2(0.f, 0.f);
    const float* base = cw + 2 * tid;
    for (int w = 0; w < Ww; ++w) {
      float2 x = *(const float2*)(base + (size_t)w * Dd);
      float bw = beta_s[w];
      cf.x += bw * x.x;
      cf.y += bw * x.y;
    }
    cfB[2 * tid]     = cf.x * inv * B[2 * tid];
    cfB[2 * tid + 1] = cf.y * inv * B[2 * tid + 1];
  }
  __syncthreads();

  // ---- scores[m][c] = <e_c, cfB> ----
  if (tid < 128) {
    int c = tid >> 4, lane = tid & 15;
    float p = 0.f;
    for (int d = lane; d < Dd; d += 16) p += cev[c * Dd + d] * cfB[d];
#pragma unroll
    for (int off = 8; off; off >>= 1) p += __shfl_down(p, off, 16);
    if (lane == 0) { scores[m * Cc + c] = p; col0[m * Cc + c] = p; }
  }
}

// ---------------------------------------------------------------------------
// bf16 conversion: Ah = bf16(X*Cl), Bh = bf16(X), K padded 300->320 w/ zeros
// ---------------------------------------------------------------------------
__global__ __launch_bounds__(256) void k_convert(
    const float* __restrict__ X,   // [MC][D]
    const float* __restrict__ Cl,  // [D]
    __bf16* __restrict__ Ah,       // [MC][KP]
    __bf16* __restrict__ Bh)       // [MC][KP]
{
  int idx = blockIdx.x * 256 + threadIdx.x;
  if (idx >= MC * KP) return;
  int j = idx / KP, k = idx - j * KP;
  float x = 0.f, cl = 0.f;
  if (k < Dd) { x = X[(size_t)j * Dd + k]; cl = Cl[k]; }
  Bh[idx] = (__bf16)x;
  Ah[idx] = (__bf16)(x * cl);
}

// ---------------------------------------------------------------------------
// Kernel 2: P = Ah @ Bh^T  [3200 x 3200], K=320, bf16 MFMA, fp32 accum
// 128x128 tile, 4 waves (2x2), each wave 64x64 via 4x4 16x16x32 fragments.
// ---------------------------------------------------------------------------
__global__ __launch_bounds__(256) void k_pairwise_mfma(
    const __bf16* __restrict__ Ah,  // [MC][KP]
    const __bf16* __restrict__ Bh,  // [MC][KP]
    float* __restrict__ P)          // [MC][MC]
{
  __shared__ __align__(16) __bf16 As[128 * 32];  // 8 KB
  __shared__ __align__(16) __bf16 Bs[128 * 32];  // 8 KB
  const int tid = threadIdx.x;
  const int wave = tid >> 6, lane = tid & 63;
  const int wr = wave >> 1, wc = wave & 1;      // 2x2 wave grid
  const int row0 = blockIdx.y * 128, col0 = blockIdx.x * 128;

  f32x4 acc[4][4] = {};
  const int fr = lane & 15, fq = lane >> 4;
  const int koff = fq * 8;

  for (int kt = 0; kt < KP / 32; ++kt) {
    const int k0 = kt * 32;
#pragma unroll
    for (int i = 0; i < 2; ++i) {
      int e = i * 256 + tid;
      int r = e >> 2;
      int kc = (e & 3) << 3;
      gload16(Ah + (size_t)(row0 + r) * KP + k0 + kc, (char*)As + e * 16);
      gload16(Bh + (size_t)(col0 + r) * KP + k0 + kc, (char*)Bs + e * 16);
    }
    __syncthreads();

    bf16x8 af[4], bfr[4];
#pragma unroll
    for (int mi = 0; mi < 4; ++mi)
      af[mi] = *(const bf16x8*)&As[(wr * 64 + mi * 16 + fr) * 32 + koff];
#pragma unroll
    for (int ni = 0; ni < 4; ++ni)
      bfr[ni] = *(const bf16x8*)&Bs[(wc * 64 + ni * 16 + fr) * 32 + koff];
#pragma unroll
    for (int mi = 0; mi < 4; ++mi)
#pragma unroll
      for (int ni = 0; ni < 4; ++ni)
        acc[mi][ni] = __builtin_amdgcn_mfma_f32_16x16x32_bf16(
            af[mi], bfr[ni], acc[mi][ni], 0, 0, 0);
    __syncthreads();
  }

#pragma unroll
  for (int mi = 0; mi < 4; ++mi)
#pragma unroll
    for (int ni = 0; ni < 4; ++ni) {
      size_t base = (size_t)(row0 + wr * 64 + mi * 16 + fq * 4) * MC +
                    col0 + wc * 64 + ni * 16 + fr;
#pragma unroll
      for (int r = 0; r < 4; ++r)
        P[base + (size_t)r * MC] = acc[mi][ni][r];
    }
}

// ---------------------------------------------------------------------------
// LBP step (fused col production)
// ---------------------------------------------------------------------------
__global__ __launch_bounds__(256) void k_lbp(
    const float* __restrict__ P,
    const float* __restrict__ colIn,
    const float* __restrict__ scores,
    float* __restrict__ msg,
    float* __restrict__ colOut)
{
  const int aa = blockIdx.x;
  __shared__ __align__(16) float col_s[MC];
  __shared__ float red_s[4][Cc];
  for (int i = threadIdx.x; i < MC; i += 256) col_s[i] = colIn[i];
  __syncthreads();

  float psum[Cc];
#pragma unroll
  for (int b = 0; b < Cc; ++b) psum[b] = 0.f;

  for (int m = threadIdx.x; m < Mm; m += 256) {
    const float4 c0 = *reinterpret_cast<const float4*>(&col_s[m * 8]);
    const float4 c1 = *reinterpret_cast<const float4*>(&col_s[m * 8 + 4]);
    float t[Cc];
#pragma unroll
    for (int b = 0; b < Cc; ++b) {
      const float* prow = P + (size_t)(aa * 8 + b) * MC + m * 8;
      float4 p0 = *reinterpret_cast<const float4*>(prow);
      float4 p1 = *reinterpret_cast<const float4*>(prow + 4);
      float tb = fmaxf(fmaxf(p0.x + c0.x, p0.y + c0.y), fmaxf(p0.z + c0.z, p0.w + c0.w));
      t[b] = fmaxf(tb, fmaxf(fmaxf(p1.x + c1.x, p1.y + c1.y), fmaxf(p1.z + c1.z, p1.w + c1.w)));
    }
    float mxt = t[0];
#pragma unroll
    for (int b = 1; b < Cc; ++b) mxt = fmaxf(mxt, t[b]);
    float se = 0.f;
#pragma unroll
    for (int b = 0; b < Cc; ++b) se += expf(t[b] - mxt);
    float lse = mxt + logf(se);
    bool self = (m == aa);
#pragma unroll
    for (int b = 0; b < Cc; ++b) {
      float sel = self ? 0.f : (t[b] - lse);
      size_t mi = (size_t)(aa * 8 + b) * Mm + m;
      float old = msg[mi];
      float nv = logf(0.5f * expf(sel) + 0.5f * expf(old));
      msg[mi] = nv;
      psum[b] += nv;
    }
  }

  const int wave = threadIdx.x >> 6, lane = threadIdx.x & 63;
#pragma unroll
  for (int b = 0; b < Cc; ++b)
#pragma unroll
    for (int off = 32; off; off >>= 1) psum[b] += __shfl_down(psum[b], off);
  if (lane == 0)
#pragma unroll
    for (int b = 0; b < Cc; ++b) red_s[wave][b] = psum[b];
  __syncthreads();
  if (threadIdx.x < Cc) {
    int b = threadIdx.x;
    float s = red_s[0][b] + red_s[1][b] + red_s[2][b] + red_s[3][b];
    colOut[aa * Cc + b] = scores[aa * Cc + b] + s;
  }
}

// ---------------------------------------------------------------------------
// Final: fgs = log_softmax(colF, axis=C); tiny MLP. One thread per mention.
// ---------------------------------------------------------------------------
__global__ __launch_bounds__(64) void k_final2(
    const float* __restrict__ colF,    // [MC]
    const float* __restrict__ pem,     // [MC]
    const float* __restrict__ W1,      // [H][2]
    const float* __restrict__ b1,      // [H]
    const float* __restrict__ W2,      // [H]
    const float* __restrict__ b2,      // [1]
    float* __restrict__ out)           // [MC]
{
  int m = blockIdx.x * 64 + threadIdx.x;
  if (m >= Mm) return;
  float f[Cc], pm[Cc];
#pragma unroll
  for (int c = 0; c < Cc; ++c) {
    f[c] = colF[m * Cc + c];
    pm[c] = pem[m * Cc + c];
  }
  float mx = f[0];
#pragma unroll
  for (int c = 1; c < Cc; ++c) mx = fmaxf(mx, f[c]);
  float se = 0.f;
#pragma unroll
  for (int c = 0; c < Cc; ++c) se += expf(f[c] - mx);
  float lse = mx + logf(se);
  float fgs[Cc], accv[Cc];
  float bb2 = b2[0];
#pragma unroll
  for (int c = 0; c < Cc; ++c) { fgs[c] = f[c] - lse; accv[c] = bb2; }
  for (int h = 0; h < Hh; ++h) {
    float w0 = W1[2 * h], w1 = W1[2 * h + 1], bb = b1[h], w2 = W2[h];
#pragma unroll
    for (int c = 0; c < Cc; ++c)
      accv[c] += w2 * fmaxf(fgs[c] * w0 + pm[c] * w1 + bb, 0.f);
  }
#pragma unroll
  for (int c = 0; c < Cc; ++c) out[m * Cc + c] = accv[c];
}

// ---------------------------------------------------------------------------
extern "C" void kernel_launch(void* const* d_in, const int* in_sizes, int n_in,
                              void* d_out, int out_size, void* d_ws, size_t ws_size,
                              hipStream_t stream) {
  const float* ctxt_vec = (const float*)d_in[1];   // [M][W][D]
  const float* cand_vec = (const float*)d_in[3];   // [M][C][D]
  const float* pem      = (const float*)d_in[4];   // [M][C]
  const float* A        = (const float*)d_in[5];
  const float* B        = (const float*)d_in[6];
  const float* Cl       = (const float*)d_in[7];
  const float* W1       = (const float*)d_in[8];
  const float* b1       = (const float*)d_in[9];
  const float* W2       = (const float*)d_in[10];
  const float* b2       = (const float*)d_in[11];
  float* out = (float*)d_out;

  char* ws = (char*)d_ws;
  float*  P      = (float*)(ws);                          // 40,960,000 B
  float*  msg    = (float*)(ws + 40960000);               //  5,120,000 B
  __bf16* Ah     = (__bf16*)(ws + 40960000);              // alias msg (pre-memset)
  __bf16* Bh     = (__bf16*)(ws + 40960000 + 2048000);
  float*  scores = (float*)(ws + 46080000);
  float*  col0   = scores + MC;
  float*  col1   = col0 + MC;

  k_convert<<<(MC * KP + 255) / 256, 256, 0, stream>>>(cand_vec, Cl, Ah, Bh);
  k_entity_context<<<Mm, 256, 0, stream>>>(ctxt_vec, cand_vec, A, B, scores, col0);

  dim3 g(MC / 128, MC / 128);
  k_pairwise_mfma<<<g, 256, 0, stream>>>(Ah, Bh, P);

  hipMemsetAsync(msg, 0, (size_t)MC * Mm * sizeof(float), stream);  // after GEMM (alias!)

  float* cIn = col0; float* cOut = col1;
  for (int it = 0; it < LBP_ITERS; ++it) {
    k_lbp<<<Mm, 256, 0, stream>>>(P, cIn, scores, msg, cOut);
    float* t = cIn; cIn = cOut; cOut = t;
  }
  k_final2<<<(Mm + 63) / 64, 64, 0, stream>>>(cIn, pem, W1, b1, W2, b2, out);
}